// Round 10
// baseline (282.297 us; speedup 1.0000x reference)
//
#include <hip/hip_runtime.h>

#define NN 20000      // nodes
#define FIN 256
#define D1 1024       // H1*C1 = 8*128
#define NH 8
#define C2 128
#define CAP 64        // padded CSR bucket capacity (max degree ~35 incl. self-loop)

typedef unsigned short u16;
typedef unsigned char u8;
typedef __attribute__((ext_vector_type(8))) short bf16x8;
typedef __attribute__((ext_vector_type(4))) float f32x4;
typedef __attribute__((ext_vector_type(2))) float f32x2;

// ---------- bf16 helpers ----------
__device__ __forceinline__ float bf2f(u16 u) {
    return __uint_as_float(((unsigned int)u) << 16);
}
__device__ __forceinline__ u16 f2bf(float f) {
    unsigned int u = __float_as_uint(f);
    u += 0x7FFFu + ((u >> 16) & 1u);   // round-to-nearest-even
    return (u16)(u >> 16);
}
// ---------- fp8 e4m3 (OCP) helpers via HW converts ----------
__device__ __forceinline__ u8 f2fp8(float v) {
    int q = __builtin_amdgcn_cvt_pk_fp8_f32(v, v, 0, false);
    return (u8)(q & 0xFF);
}
__device__ __forceinline__ void fp8x4_to_f32(unsigned int w, float* o) {
    f32x2 lo = __builtin_amdgcn_cvt_pk_f32_fp8(w, false);
    f32x2 hi = __builtin_amdgcn_cvt_pk_f32_fp8(w, true);
    o[0] = lo[0]; o[1] = lo[1]; o[2] = hi[0]; o[3] = hi[1];
}

// butterfly reductions: every lane ends with the result
__device__ __forceinline__ float bred_max(float v) {
    #pragma unroll
    for (int o = 32; o > 0; o >>= 1) v = fmaxf(v, __shfl_xor(v, o, 64));
    return v;
}
__device__ __forceinline__ float bred_sum(float v) {
    #pragma unroll
    for (int o = 32; o > 0; o >>= 1) v += __shfl_xor(v, o, 64);
    return v;
}

// async global->LDS, 16B per lane (global_load_lds_dwordx4)
typedef const __attribute__((address_space(1))) unsigned int* as1_u32p;
typedef __attribute__((address_space(3))) unsigned int* as3_u32p;
__device__ __forceinline__ void gload_lds16(const void* g, void* l) {
    __builtin_amdgcn_global_load_lds((as1_u32p)g, (as3_u32p)l, 16, 0, 0);
}

// ---------- fp32 -> bf16 cast (vectorized) ----------
__global__ __launch_bounds__(256) void cast_bf16_kernel(const float* __restrict__ in,
                                                        u16* __restrict__ out, int n4) {
    int i = (blockIdx.x * 256 + threadIdx.x) * 4;
    if (i < n4) {
        float4 v = *(const float4*)(in + i);
        ushort4 o;
        o.x = f2bf(v.x); o.y = f2bf(v.y); o.z = f2bf(v.z); o.w = f2bf(v.w);
        *(ushort4*)(out + i) = o;
    }
}

// ---------- fp32 [R][C] -> bf16 [C][R] transpose-cast (32x32 LDS tiles) ----------
__global__ __launch_bounds__(256) void transpose_cast_kernel(const float* __restrict__ in,
                                                             u16* __restrict__ out,
                                                             int R, int C) {
    __shared__ float tile[32][33];
    int bx = blockIdx.x * 32;  // col base in input
    int by = blockIdx.y * 32;  // row base in input
    int tx = threadIdx.x & 31, ty = threadIdx.x >> 5;  // 32x8
    #pragma unroll
    for (int i = 0; i < 32; i += 8)
        tile[ty + i][tx] = in[(size_t)(by + ty + i) * C + bx + tx];
    __syncthreads();
    #pragma unroll
    for (int i = 0; i < 32; i += 8)
        out[(size_t)(bx + ty + i) * R + by + tx] = f2bf(tile[tx][ty + i]);
}

// ---------- bf16 MFMA GEMM (BK=64) with fused attention-score epilogue ----------
// C[MxN] = A[MxK] * Bt[NxK]^T.  Block col bj covers cols [bj*128,(bj+1)*128)
// = exactly one attention head, so each block computes COMPLETE per-row
// as/ad = sum_col h[row][col]*att[col] from its fp32 accumulators.
// OMODE 1: bf16 C out (layer 2; head=0, NHo=1)
// OMODE 2: fp8 e4m3 C out only (layer 1; head=blockIdx.y, NHo=8)
template <int BM, int OMODE>
__global__ __launch_bounds__(256) void gemm_mfma(const u16* __restrict__ A,
                                                 const u16* __restrict__ Bt,
                                                 void* __restrict__ C,
                                                 const float* __restrict__ attS,
                                                 const float* __restrict__ attD,
                                                 float* __restrict__ as_out,
                                                 float* __restrict__ ad_out,
                                                 int NHo,
                                                 int M, int N, int K) {
    constexpr int TM = BM / 32;            // 16-tiles per wave along m
    __shared__ u16 ldsA[BM * 64];          // BK=64
    __shared__ u16 ldsB[128 * 64];
    __shared__ float asb[BM], adb[BM];
    const int tid = threadIdx.x;
    const int lane = tid & 63, w = tid >> 6;
    const int wr = w >> 1, wc = w & 1;
    const int row0 = blockIdx.x * BM, col0 = blockIdx.y * 128;
    const int head = blockIdx.y;
    const int l15 = lane & 15, quad = lane >> 4;

    for (int t = tid; t < BM; t += 256) { asb[t] = 0.f; adb[t] = 0.f; }

    f32x4 acc[TM][4];
    #pragma unroll
    for (int i = 0; i < TM; i++)
        #pragma unroll
        for (int j = 0; j < 4; j++)
            acc[i][j] = (f32x4){0.f, 0.f, 0.f, 0.f};

    for (int k0 = 0; k0 < K; k0 += 64) {
        // stage A tile: BM rows x 64 k (128B/row = 8 chunks of 16B)
        #pragma unroll
        for (int i = 0; i < BM / 32; i++) {
            int c = tid + i * 256;
            int r = c >> 3, ko = (c & 7) * 8;
            int gr = row0 + r; if (gr >= M) gr = M - 1;  // clamp: rows >=M never stored
            gload_lds16(A + (size_t)gr * K + k0 + ko, ldsA + c * 8);
        }
        // stage B tile: 128 n-rows x 64 k
        #pragma unroll
        for (int i = 0; i < 4; i++) {
            int c = tid + i * 256;
            int n = c >> 3, ko = (c & 7) * 8;
            gload_lds16(Bt + (size_t)(col0 + n) * K + k0 + ko, ldsB + c * 8);
        }
        __syncthreads();
        #pragma unroll
        for (int kk = 0; kk < 2; kk++) {
            bf16x8 af[TM], bfr[4];
            #pragma unroll
            for (int i = 0; i < TM; i++) {
                int m = wr * (BM / 2) + i * 16 + l15;
                af[i] = *(const bf16x8*)(ldsA + m * 64 + kk * 32 + quad * 8);
            }
            #pragma unroll
            for (int j = 0; j < 4; j++) {
                int n = wc * 64 + j * 16 + l15;
                bfr[j] = *(const bf16x8*)(ldsB + n * 64 + kk * 32 + quad * 8);
            }
            #pragma unroll
            for (int i = 0; i < TM; i++)
                #pragma unroll
                for (int j = 0; j < 4; j++)
                    acc[i][j] = __builtin_amdgcn_mfma_f32_16x16x32_bf16(af[i], bfr[j], acc[i][j], 0, 0, 0);
        }
        __syncthreads();
    }
    // ---- C write (fp8 for layer1, bf16 for layer2) ----
    #pragma unroll
    for (int i = 0; i < TM; i++) {
        #pragma unroll
        for (int j = 0; j < 4; j++) {
            #pragma unroll
            for (int r = 0; r < 4; r++) {
                int row = row0 + wr * (BM / 2) + i * 16 + quad * 4 + r;
                int col = col0 + wc * 64 + j * 16 + l15;
                if (row < M) {
                    float v = acc[i][j][r];
                    if (OMODE == 1)
                        ((u16*)C)[(size_t)row * N + col] = f2bf(v);
                    else
                        ((u8*)C)[(size_t)row * N + col] = f2fp8(v);
                }
            }
        }
    }
    // ---- fused per-row attention dots for this head ----
    float attS_r[4], attD_r[4];
    #pragma unroll
    for (int j = 0; j < 4; j++) {
        int col = wc * 64 + j * 16 + l15;
        attS_r[j] = attS[head * 128 + col];
        attD_r[j] = attD[head * 128 + col];
    }
    #pragma unroll
    for (int i = 0; i < TM; i++) {
        #pragma unroll
        for (int r = 0; r < 4; r++) {
            float ps = 0.f, pd = 0.f;
            #pragma unroll
            for (int j = 0; j < 4; j++) {
                float v = acc[i][j][r];
                ps = fmaf(v, attS_r[j], ps);
                pd = fmaf(v, attD_r[j], pd);
            }
            #pragma unroll
            for (int o = 1; o < 16; o <<= 1) {
                ps += __shfl_xor(ps, o, 64);
                pd += __shfl_xor(pd, o, 64);
            }
            if (l15 == 0) {
                int row = wr * (BM / 2) + i * 16 + quad * 4 + r;
                atomicAdd(&asb[row], ps);
                atomicAdd(&adb[row], pd);
            }
        }
    }
    __syncthreads();
    for (int t = tid; t < BM; t += 256) {
        int row = row0 + t;
        if (row < M) {
            as_out[(size_t)row * NHo + head] = asb[t];
            ad_out[(size_t)row * NHo + head] = adb[t];
        }
    }
}

// ---------- zero per-node counters ----------
__global__ void init_cnt_kernel(int* cnt, int N) {
    int i = blockIdx.x * 256 + threadIdx.x;
    if (i < N) cnt[i] = 0;
}

// ---------- padded-bucket CSR fill + layer-1 edge weights (8 heads) ----------
__global__ void fill_kernel(const int* __restrict__ ei, int E, int N,
                            int* __restrict__ cnt,
                            int* __restrict__ csr,
                            const float* __restrict__ as1,
                            const float* __restrict__ ad1,
                            float* __restrict__ pw1) {
    int j = blockIdx.x * 256 + threadIdx.x;
    if (j >= E + N) return;
    int s, d;
    if (j < E) { s = ei[j]; d = ei[E + j]; }
    else { s = j - E; d = j - E; }
    int pos = atomicAdd(&cnt[d], 1);
    if (pos >= CAP) return;   // safety net (never expected)
    int slot = d * CAP + pos;
    csr[slot] = s;
    float4 s0 = *(const float4*)(as1 + s * NH);
    float4 s1 = *(const float4*)(as1 + s * NH + 4);
    float4 d0 = *(const float4*)(ad1 + d * NH);
    float4 d1 = *(const float4*)(ad1 + d * NH + 4);
    float e[8] = {s0.x + d0.x, s0.y + d0.y, s0.z + d0.z, s0.w + d0.w,
                  s1.x + d1.x, s1.y + d1.y, s1.z + d1.z, s1.w + d1.w};
    float p[8];
    #pragma unroll
    for (int h = 0; h < 8; h++) {
        float v = e[h] > 0.f ? e[h] : 0.2f * e[h];
        p[h] = __expf(v);
    }
    *(float4*)(pw1 + (size_t)slot * 8) = *(const float4*)p;
    *(float4*)(pw1 + (size_t)slot * 8 + 4) = *(const float4*)(p + 4);
}

// ---------- layer-1 softmax-aggregate + ELU ----------
// ONE WAVE per dst, padded bucket. Coalesced csr load, idx broadcast via
// shfl; pre-computed weights (sequential read); x8 unroll -> 8 independent
// 16B fp8 gathers in flight. No LDS/barriers/atomics.
#define A1_STEP(QQ, PP)                                              \
    do {                                                             \
        float f_[16];                                                \
        fp8x4_to_f32((QQ).x, f_ + 0); fp8x4_to_f32((QQ).y, f_ + 4);  \
        fp8x4_to_f32((QQ).z, f_ + 8); fp8x4_to_f32((QQ).w, f_ + 12); \
        _Pragma("unroll")                                            \
        for (int k_ = 0; k_ < 16; k_++)                              \
            acc[k_] = fmaf((PP), f_[k_], acc[k_]);                   \
    } while (0)

__global__ __launch_bounds__(256) void agg1_kernel(const u8* __restrict__ h1q,
                                                   const float* __restrict__ pw1,
                                                   const int* __restrict__ cnt,
                                                   const int* __restrict__ csr,
                                                   const float* __restrict__ bias1,
                                                   u16* __restrict__ x2) {
    const int tid = threadIdx.x;
    const int dst = (blockIdx.x << 2) + (tid >> 6);
    const int lane = tid & 63;
    if (dst >= NN) return;
    const int c0 = lane * 16;               // 16 channels per lane
    const int h = lane >> 3;                // head
    const int base = dst * CAP;
    const int deg = max(1, min(cnt[dst], CAP));

    float acc[16];
    #pragma unroll
    for (int k = 0; k < 16; k++) acc[k] = 0.f;
    float den = 0.f;

    int idx = csr[base + min(lane, deg - 1)];       // coalesced
    const float* pwc = pw1 + (size_t)base * 8 + h;  // sequential (stride 32B)
    int j = 0;
    for (; j + 8 <= deg; j += 8) {
        int s0 = __shfl(idx, j, 64),     s1 = __shfl(idx, j + 1, 64);
        int s2 = __shfl(idx, j + 2, 64), s3 = __shfl(idx, j + 3, 64);
        int s4 = __shfl(idx, j + 4, 64), s5 = __shfl(idx, j + 5, 64);
        int s6 = __shfl(idx, j + 6, 64), s7 = __shfl(idx, j + 7, 64);
        uint4 q0 = *(const uint4*)(h1q + (size_t)s0 * D1 + c0);
        uint4 q1 = *(const uint4*)(h1q + (size_t)s1 * D1 + c0);
        uint4 q2 = *(const uint4*)(h1q + (size_t)s2 * D1 + c0);
        uint4 q3 = *(const uint4*)(h1q + (size_t)s3 * D1 + c0);
        uint4 q4 = *(const uint4*)(h1q + (size_t)s4 * D1 + c0);
        uint4 q5 = *(const uint4*)(h1q + (size_t)s5 * D1 + c0);
        uint4 q6 = *(const uint4*)(h1q + (size_t)s6 * D1 + c0);
        uint4 q7 = *(const uint4*)(h1q + (size_t)s7 * D1 + c0);
        float p0 = pwc[(j + 0) * 8], p1 = pwc[(j + 1) * 8];
        float p2 = pwc[(j + 2) * 8], p3 = pwc[(j + 3) * 8];
        float p4 = pwc[(j + 4) * 8], p5 = pwc[(j + 5) * 8];
        float p6 = pwc[(j + 6) * 8], p7 = pwc[(j + 7) * 8];
        den += ((p0 + p1) + (p2 + p3)) + ((p4 + p5) + (p6 + p7));
        A1_STEP(q0, p0); A1_STEP(q1, p1); A1_STEP(q2, p2); A1_STEP(q3, p3);
        A1_STEP(q4, p4); A1_STEP(q5, p5); A1_STEP(q6, p6); A1_STEP(q7, p7);
    }
    for (; j + 4 <= deg; j += 4) {
        int s0 = __shfl(idx, j, 64),     s1 = __shfl(idx, j + 1, 64);
        int s2 = __shfl(idx, j + 2, 64), s3 = __shfl(idx, j + 3, 64);
        uint4 q0 = *(const uint4*)(h1q + (size_t)s0 * D1 + c0);
        uint4 q1 = *(const uint4*)(h1q + (size_t)s1 * D1 + c0);
        uint4 q2 = *(const uint4*)(h1q + (size_t)s2 * D1 + c0);
        uint4 q3 = *(const uint4*)(h1q + (size_t)s3 * D1 + c0);
        float p0 = pwc[(j + 0) * 8], p1 = pwc[(j + 1) * 8];
        float p2 = pwc[(j + 2) * 8], p3 = pwc[(j + 3) * 8];
        den += (p0 + p1) + (p2 + p3);
        A1_STEP(q0, p0); A1_STEP(q1, p1); A1_STEP(q2, p2); A1_STEP(q3, p3);
    }
    for (; j < deg; j++) {
        int s = __shfl(idx, j, 64);
        float p = pwc[j * 8];
        uint4 q = *(const uint4*)(h1q + (size_t)s * D1 + c0);
        den += p;
        A1_STEP(q, p);
    }

    float inv = 1.f / (den + 1e-16f);
    u16 ov[16];
    #pragma unroll
    for (int k = 0; k < 16; k++) {
        float a = acc[k] * inv + bias1[c0 + k];
        a = a > 0.f ? a : expm1f(a);   // ELU
        ov[k] = f2bf(a);
    }
    *(uint4*)(x2 + (size_t)dst * D1 + c0) = *(const uint4*)ov;
    *(uint4*)(x2 + (size_t)dst * D1 + c0 + 8) = *(const uint4*)(ov + 8);
}

// ---------- layer-2 per-edge weights (padded slots, fully parallel) ----------
__global__ __launch_bounds__(256) void edgew2_kernel(const int* __restrict__ csr,
                                                     const int* __restrict__ cnt,
                                                     const float* __restrict__ as2,
                                                     const float* __restrict__ ad2,
                                                     float* __restrict__ pw2) {
    int i = blockIdx.x * 256 + threadIdx.x;
    if (i >= NN * CAP) return;
    int d = i / CAP, pos = i % CAP;
    if (pos < min(cnt[d], CAP)) {
        float e = as2[csr[i]] + ad2[d];
        e = e > 0.f ? e : 0.2f * e;
        pw2[i] = __expf(e);
    }
}

// ---------- layer-2 softmax-aggregate + log_softmax ----------
// ONE WAVE per dst; idx+weight broadcast via shfl; 4B bf16 gather per edge,
// x8 unroll for MLP.
__global__ __launch_bounds__(256) void agg2_kernel(const u16* __restrict__ h2,
                                                   const float* __restrict__ pw2,
                                                   const int* __restrict__ cnt,
                                                   const int* __restrict__ csr,
                                                   const float* __restrict__ bias2,
                                                   float* __restrict__ out) {
    const int tid = threadIdx.x;
    const int dst = (blockIdx.x << 2) + (tid >> 6);
    const int lane = tid & 63;
    if (dst >= NN) return;
    const int base = dst * CAP;
    const int deg = max(1, min(cnt[dst], CAP));

    float a0 = 0.f, a1 = 0.f, den = 0.f;
    int lidx = base + min(lane, deg - 1);
    int idx = csr[lidx];          // coalesced
    float pl = pw2[lidx];         // coalesced
    int j = 0;
    for (; j + 8 <= deg; j += 8) {
        unsigned int v[8];
        float p[8];
        #pragma unroll
        for (int t = 0; t < 8; t++) {
            int s = __shfl(idx, j + t, 64);
            p[t] = __shfl(pl, j + t, 64);
            v[t] = *(const unsigned int*)(h2 + (size_t)s * C2 + lane * 2);
        }
        #pragma unroll
        for (int t = 0; t < 8; t++) {
            den += p[t];
            a0 = fmaf(p[t], bf2f((u16)(v[t] & 0xFFFF)), a0);
            a1 = fmaf(p[t], bf2f((u16)(v[t] >> 16)), a1);
        }
    }
    for (; j < deg; j++) {
        int s = __shfl(idx, j, 64);
        float p = __shfl(pl, j, 64);
        unsigned int v = *(const unsigned int*)(h2 + (size_t)s * C2 + lane * 2);
        den += p;
        a0 = fmaf(p, bf2f((u16)(v & 0xFFFF)), a0);
        a1 = fmaf(p, bf2f((u16)(v >> 16)), a1);
    }
    float inv = 1.f / (den + 1e-16f);
    float l0 = a0 * inv + bias2[lane * 2];
    float l1 = a1 * inv + bias2[lane * 2 + 1];
    // log_softmax over the wave's 128 channels
    float m = bred_max(fmaxf(l0, l1));
    float ex = bred_sum(expf(l0 - m) + expf(l1 - m));
    float lse = m + logf(ex);
    float2 ov = {l0 - lse, l1 - lse};
    *(float2*)(out + (size_t)dst * C2 + lane * 2) = ov;
}

extern "C" void kernel_launch(void* const* d_in, const int* in_sizes, int n_in,
                              void* d_out, int out_size, void* d_ws, size_t ws_size,
                              hipStream_t stream) {
    const float* x        = (const float*)d_in[0];
    const int*   ei       = (const int*)d_in[1];
    const float* W1       = (const float*)d_in[2];
    const float* att_src1 = (const float*)d_in[3];
    const float* att_dst1 = (const float*)d_in[4];
    const float* bias1    = (const float*)d_in[5];
    const float* W2       = (const float*)d_in[6];
    const float* att_src2 = (const float*)d_in[7];
    const float* att_dst2 = (const float*)d_in[8];
    const float* bias2    = (const float*)d_in[9];
    float* out = (float*)d_out;
    const int E = in_sizes[1] / 2;
    const int NB = (NN + 255) / 256;

    char* ws = (char*)d_ws;
    size_t off = 0;
    auto alloc = [&](size_t b) {
        void* p = ws + off;
        off += (b + 255) & ~(size_t)255;
        return p;
    };
    u8*  h1q  = (u8*)alloc((size_t)NN * D1);
    u16* x2   = (u16*)alloc((size_t)NN * D1 * 2);
    u16* h2   = (u16*)alloc((size_t)NN * C2 * 2);
    u16* xb   = (u16*)alloc((size_t)NN * FIN * 2);
    u16* w1t  = (u16*)alloc((size_t)D1 * FIN * 2);
    u16* w2t  = (u16*)alloc((size_t)C2 * D1 * 2);
    float* as1 = (float*)alloc((size_t)NN * NH * 4);
    float* ad1 = (float*)alloc((size_t)NN * NH * 4);
    float* as2 = (float*)alloc((size_t)NN * 4);
    float* ad2 = (float*)alloc((size_t)NN * 4);
    int* cnt  = (int*)alloc((size_t)NN * 4);
    int* csr  = (int*)alloc((size_t)NN * CAP * 4);
    float* pw1 = (float*)alloc((size_t)NN * CAP * 8 * 4);
    float* pw2 = (float*)alloc((size_t)NN * CAP * 4);

    cast_bf16_kernel<<<(NN * FIN / 4 + 255) / 256, 256, 0, stream>>>(x, xb, NN * FIN);
    transpose_cast_kernel<<<dim3(D1 / 32, FIN / 32), 256, 0, stream>>>(W1, w1t, FIN, D1);
    transpose_cast_kernel<<<dim3(C2 / 32, D1 / 32), 256, 0, stream>>>(W2, w2t, D1, C2);
    init_cnt_kernel<<<NB, 256, 0, stream>>>(cnt, NN);

    // layer 1 GEMM: h1q fp8 + fused per-head as1/ad1
    gemm_mfma<128, 2><<<dim3((NN + 127) / 128, D1 / 128), 256, 0, stream>>>(
        xb, w1t, h1q, att_src1, att_dst1, as1, ad1, NH, NN, D1, FIN);
    fill_kernel<<<(E + NN + 255) / 256, 256, 0, stream>>>(ei, E, NN, cnt, csr,
                                                          as1, ad1, pw1);
    // 1 wave per dst: 20000 waves = 5000 blocks
    agg1_kernel<<<(NN + 3) / 4, 256, 0, stream>>>(h1q, pw1, cnt, csr, bias1, x2);
    // layer 2 GEMM: h2 bf16 + fused as2/ad2
    gemm_mfma<64, 1><<<dim3((NN + 63) / 64, C2 / 128), 256, 0, stream>>>(
        x2, w2t, h2, att_src2, att_dst2, as2, ad2, 1, NN, C2, D1);
    edgew2_kernel<<<(NN * CAP + 255) / 256, 256, 0, stream>>>(csr, cnt, as2, ad2, pw2);
    agg2_kernel<<<(NN + 3) / 4, 256, 0, stream>>>(h2, pw2, cnt, csr, bias2, out);
}

// Round 13
// 275.026 us; speedup vs baseline: 1.0264x; 1.0264x over previous
//
#include <hip/hip_runtime.h>

#define NN 20000      // nodes
#define FIN 256
#define D1 1024       // H1*C1 = 8*128
#define NH 8
#define C2 128
#define CAP 64        // padded CSR bucket capacity (max degree ~35 incl. self-loop)

typedef unsigned short u16;
typedef unsigned char u8;
typedef __attribute__((ext_vector_type(8))) short bf16x8;
typedef __attribute__((ext_vector_type(4))) float f32x4;
typedef __attribute__((ext_vector_type(2))) float f32x2;

// ---------- bf16 helpers ----------
__device__ __forceinline__ float bf2f(u16 u) {
    return __uint_as_float(((unsigned int)u) << 16);
}
__device__ __forceinline__ u16 f2bf(float f) {
    unsigned int u = __float_as_uint(f);
    u += 0x7FFFu + ((u >> 16) & 1u);   // round-to-nearest-even
    return (u16)(u >> 16);
}
// ---------- fp8 e4m3 (OCP) helpers via HW converts ----------
__device__ __forceinline__ u8 f2fp8(float v) {
    int q = __builtin_amdgcn_cvt_pk_fp8_f32(v, v, 0, false);
    return (u8)(q & 0xFF);
}
__device__ __forceinline__ void fp8x4_to_f32(unsigned int w, float* o) {
    f32x2 lo = __builtin_amdgcn_cvt_pk_f32_fp8(w, false);
    f32x2 hi = __builtin_amdgcn_cvt_pk_f32_fp8(w, true);
    o[0] = lo[0]; o[1] = lo[1]; o[2] = hi[0]; o[3] = hi[1];
}

// butterfly reductions: every lane ends with the result
__device__ __forceinline__ float bred_max(float v) {
    #pragma unroll
    for (int o = 32; o > 0; o >>= 1) v = fmaxf(v, __shfl_xor(v, o, 64));
    return v;
}
__device__ __forceinline__ float bred_sum(float v) {
    #pragma unroll
    for (int o = 32; o > 0; o >>= 1) v += __shfl_xor(v, o, 64);
    return v;
}

// async global->LDS, 16B per lane (global_load_lds_dwordx4)
typedef const __attribute__((address_space(1))) unsigned int* as1_u32p;
typedef __attribute__((address_space(3))) unsigned int* as3_u32p;
__device__ __forceinline__ void gload_lds16(const void* g, void* l) {
    __builtin_amdgcn_global_load_lds((as1_u32p)g, (as3_u32p)l, 16, 0, 0);
}

// ---------- fp32 -> bf16 cast (vectorized) ----------
__global__ __launch_bounds__(256) void cast_bf16_kernel(const float* __restrict__ in,
                                                        u16* __restrict__ out, int n4) {
    int i = (blockIdx.x * 256 + threadIdx.x) * 4;
    if (i < n4) {
        float4 v = *(const float4*)(in + i);
        ushort4 o;
        o.x = f2bf(v.x); o.y = f2bf(v.y); o.z = f2bf(v.z); o.w = f2bf(v.w);
        *(ushort4*)(out + i) = o;
    }
}

// ---------- fp32 [R][C] -> bf16 [C][R] transpose-cast (32x32 LDS tiles) ----------
__global__ __launch_bounds__(256) void transpose_cast_kernel(const float* __restrict__ in,
                                                             u16* __restrict__ out,
                                                             int R, int C) {
    __shared__ float tile[32][33];
    int bx = blockIdx.x * 32;  // col base in input
    int by = blockIdx.y * 32;  // row base in input
    int tx = threadIdx.x & 31, ty = threadIdx.x >> 5;  // 32x8
    #pragma unroll
    for (int i = 0; i < 32; i += 8)
        tile[ty + i][tx] = in[(size_t)(by + ty + i) * C + bx + tx];
    __syncthreads();
    #pragma unroll
    for (int i = 0; i < 32; i += 8)
        out[(size_t)(bx + ty + i) * R + by + tx] = f2bf(tile[tx][ty + i]);
}

// ---------- bf16 MFMA GEMM with fused attention-score epilogue ----------
// C[MxN] = A[MxK] * Bt[NxK]^T.  Block col bj covers cols [bj*128,(bj+1)*128)
// = exactly one attention head, so each block computes COMPLETE per-row
// as/ad = sum_col h[row][col]*att[col] from its fp32 accumulators.
// OMODE 1: bf16 C out (layer 2; head=0, NHo=1)
// OMODE 2: fp8 e4m3 C out only (layer 1; head=blockIdx.y, NHo=8)
template <int BM, int OMODE>
__global__ __launch_bounds__(256) void gemm_mfma(const u16* __restrict__ A,
                                                 const u16* __restrict__ Bt,
                                                 void* __restrict__ C,
                                                 const float* __restrict__ attS,
                                                 const float* __restrict__ attD,
                                                 float* __restrict__ as_out,
                                                 float* __restrict__ ad_out,
                                                 int NHo,
                                                 int M, int N, int K) {
    constexpr int TM = BM / 32;            // 16-tiles per wave along m
    __shared__ u16 ldsA[BM * 32];
    __shared__ u16 ldsB[128 * 32];
    __shared__ float asb[BM], adb[BM];
    const int tid = threadIdx.x;
    const int lane = tid & 63, w = tid >> 6;
    const int wr = w >> 1, wc = w & 1;
    const int row0 = blockIdx.x * BM, col0 = blockIdx.y * 128;
    const int head = blockIdx.y;
    const int l15 = lane & 15, quad = lane >> 4;

    for (int t = tid; t < BM; t += 256) { asb[t] = 0.f; adb[t] = 0.f; }

    f32x4 acc[TM][4];
    #pragma unroll
    for (int i = 0; i < TM; i++)
        #pragma unroll
        for (int j = 0; j < 4; j++)
            acc[i][j] = (f32x4){0.f, 0.f, 0.f, 0.f};

    for (int k0 = 0; k0 < K; k0 += 32) {
        #pragma unroll
        for (int i = 0; i < BM / 64; i++) {
            int c = tid + i * 256;
            int r = c >> 2, ko = (c & 3) * 8;
            int gr = row0 + r; if (gr >= M) gr = M - 1;  // clamp: rows >=M never stored
            gload_lds16(A + (size_t)gr * K + k0 + ko, ldsA + c * 8);
        }
        #pragma unroll
        for (int i = 0; i < 2; i++) {
            int c = tid + i * 256;
            int n = c >> 2, ko = (c & 3) * 8;
            gload_lds16(Bt + (size_t)(col0 + n) * K + k0 + ko, ldsB + c * 8);
        }
        __syncthreads();
        bf16x8 af[TM], bfr[4];
        #pragma unroll
        for (int i = 0; i < TM; i++) {
            int m = wr * (BM / 2) + i * 16 + l15;
            af[i] = *(const bf16x8*)(ldsA + m * 32 + quad * 8);
        }
        #pragma unroll
        for (int j = 0; j < 4; j++) {
            int n = wc * 64 + j * 16 + l15;
            bfr[j] = *(const bf16x8*)(ldsB + n * 32 + quad * 8);
        }
        #pragma unroll
        for (int i = 0; i < TM; i++)
            #pragma unroll
            for (int j = 0; j < 4; j++)
                acc[i][j] = __builtin_amdgcn_mfma_f32_16x16x32_bf16(af[i], bfr[j], acc[i][j], 0, 0, 0);
        __syncthreads();
    }
    // ---- C write (fp8 for layer1, bf16 for layer2) ----
    #pragma unroll
    for (int i = 0; i < TM; i++) {
        #pragma unroll
        for (int j = 0; j < 4; j++) {
            #pragma unroll
            for (int r = 0; r < 4; r++) {
                int row = row0 + wr * (BM / 2) + i * 16 + quad * 4 + r;
                int col = col0 + wc * 64 + j * 16 + l15;
                if (row < M) {
                    float v = acc[i][j][r];
                    if (OMODE == 1)
                        ((u16*)C)[(size_t)row * N + col] = f2bf(v);
                    else
                        ((u8*)C)[(size_t)row * N + col] = f2fp8(v);
                }
            }
        }
    }
    // ---- fused per-row attention dots for this head ----
    float attS_r[4], attD_r[4];
    #pragma unroll
    for (int j = 0; j < 4; j++) {
        int col = wc * 64 + j * 16 + l15;
        attS_r[j] = attS[head * 128 + col];
        attD_r[j] = attD[head * 128 + col];
    }
    #pragma unroll
    for (int i = 0; i < TM; i++) {
        #pragma unroll
        for (int r = 0; r < 4; r++) {
            float ps = 0.f, pd = 0.f;
            #pragma unroll
            for (int j = 0; j < 4; j++) {
                float v = acc[i][j][r];
                ps = fmaf(v, attS_r[j], ps);
                pd = fmaf(v, attD_r[j], pd);
            }
            #pragma unroll
            for (int o = 1; o < 16; o <<= 1) {
                ps += __shfl_xor(ps, o, 64);
                pd += __shfl_xor(pd, o, 64);
            }
            if (l15 == 0) {
                int row = wr * (BM / 2) + i * 16 + quad * 4 + r;
                atomicAdd(&asb[row], ps);
                atomicAdd(&adb[row], pd);
            }
        }
    }
    __syncthreads();
    for (int t = tid; t < BM; t += 256) {
        int row = row0 + t;
        if (row < M) {
            as_out[(size_t)row * NHo + head] = asb[t];
            ad_out[(size_t)row * NHo + head] = adb[t];
        }
    }
}

// ---------- zero per-node counters ----------
__global__ void init_cnt_kernel(int* cnt, int N) {
    int i = blockIdx.x * 256 + threadIdx.x;
    if (i < N) cnt[i] = 0;
}

// ---------- padded-bucket CSR fill + layer-1 edge weights (8 heads) ----------
__global__ void fill_kernel(const int* __restrict__ ei, int E, int N,
                            int* __restrict__ cnt,
                            int* __restrict__ csr,
                            const float* __restrict__ as1,
                            const float* __restrict__ ad1,
                            float* __restrict__ pw1) {
    int j = blockIdx.x * 256 + threadIdx.x;
    if (j >= E + N) return;
    int s, d;
    if (j < E) { s = ei[j]; d = ei[E + j]; }
    else { s = j - E; d = j - E; }
    int pos = atomicAdd(&cnt[d], 1);
    if (pos >= CAP) return;   // safety net (never expected)
    int slot = d * CAP + pos;
    csr[slot] = s;
    float4 s0 = *(const float4*)(as1 + s * NH);
    float4 s1 = *(const float4*)(as1 + s * NH + 4);
    float4 d0 = *(const float4*)(ad1 + d * NH);
    float4 d1 = *(const float4*)(ad1 + d * NH + 4);
    float e[8] = {s0.x + d0.x, s0.y + d0.y, s0.z + d0.z, s0.w + d0.w,
                  s1.x + d1.x, s1.y + d1.y, s1.z + d1.z, s1.w + d1.w};
    float p[8];
    #pragma unroll
    for (int h = 0; h < 8; h++) {
        float v = e[h] > 0.f ? e[h] : 0.2f * e[h];
        p[h] = __expf(v);
    }
    *(float4*)(pw1 + (size_t)slot * 8) = *(const float4*)p;
    *(float4*)(pw1 + (size_t)slot * 8 + 4) = *(const float4*)(p + 4);
}

// ---------- layer-1 softmax-aggregate + ELU ----------
// ONE WAVE per dst, padded bucket. Coalesced csr load, idx broadcast via
// shfl; pre-computed weights (sequential read); x4 unroll -> 4 independent
// 16B fp8 gathers in flight. No LDS/barriers/atomics.
__global__ __launch_bounds__(256) void agg1_kernel(const u8* __restrict__ h1q,
                                                   const float* __restrict__ pw1,
                                                   const int* __restrict__ cnt,
                                                   const int* __restrict__ csr,
                                                   const float* __restrict__ bias1,
                                                   u16* __restrict__ x2) {
    const int tid = threadIdx.x;
    const int dst = (blockIdx.x << 2) + (tid >> 6);
    const int lane = tid & 63;
    if (dst >= NN) return;
    const int c0 = lane * 16;               // 16 channels per lane
    const int h = lane >> 3;                // head
    const int base = dst * CAP;
    const int deg = max(1, min(cnt[dst], CAP));

    float acc[16];
    #pragma unroll
    for (int k = 0; k < 16; k++) acc[k] = 0.f;
    float den = 0.f;

    int idx = csr[base + min(lane, deg - 1)];       // coalesced
    const float* pwc = pw1 + (size_t)base * 8 + h;  // sequential (stride 32B)
    int j = 0;
    for (; j + 4 <= deg; j += 4) {
        int s0 = __shfl(idx, j, 64),     s1 = __shfl(idx, j + 1, 64);
        int s2 = __shfl(idx, j + 2, 64), s3 = __shfl(idx, j + 3, 64);
        uint4 q0 = *(const uint4*)(h1q + (size_t)s0 * D1 + c0);
        uint4 q1 = *(const uint4*)(h1q + (size_t)s1 * D1 + c0);
        uint4 q2 = *(const uint4*)(h1q + (size_t)s2 * D1 + c0);
        uint4 q3 = *(const uint4*)(h1q + (size_t)s3 * D1 + c0);
        float p0 = pwc[(j + 0) * 8], p1 = pwc[(j + 1) * 8];
        float p2 = pwc[(j + 2) * 8], p3 = pwc[(j + 3) * 8];
        den += (p0 + p1) + (p2 + p3);
        float f[16];
        fp8x4_to_f32(q0.x, f + 0); fp8x4_to_f32(q0.y, f + 4);
        fp8x4_to_f32(q0.z, f + 8); fp8x4_to_f32(q0.w, f + 12);
        #pragma unroll
        for (int k = 0; k < 16; k++) acc[k] = fmaf(p0, f[k], acc[k]);
        fp8x4_to_f32(q1.x, f + 0); fp8x4_to_f32(q1.y, f + 4);
        fp8x4_to_f32(q1.z, f + 8); fp8x4_to_f32(q1.w, f + 12);
        #pragma unroll
        for (int k = 0; k < 16; k++) acc[k] = fmaf(p1, f[k], acc[k]);
        fp8x4_to_f32(q2.x, f + 0); fp8x4_to_f32(q2.y, f + 4);
        fp8x4_to_f32(q2.z, f + 8); fp8x4_to_f32(q2.w, f + 12);
        #pragma unroll
        for (int k = 0; k < 16; k++) acc[k] = fmaf(p2, f[k], acc[k]);
        fp8x4_to_f32(q3.x, f + 0); fp8x4_to_f32(q3.y, f + 4);
        fp8x4_to_f32(q3.z, f + 8); fp8x4_to_f32(q3.w, f + 12);
        #pragma unroll
        for (int k = 0; k < 16; k++) acc[k] = fmaf(p3, f[k], acc[k]);
    }
    for (; j < deg; j++) {
        int s = __shfl(idx, j, 64);
        float p = pwc[j * 8];
        uint4 q = *(const uint4*)(h1q + (size_t)s * D1 + c0);
        den += p;
        float f[16];
        fp8x4_to_f32(q.x, f + 0); fp8x4_to_f32(q.y, f + 4);
        fp8x4_to_f32(q.z, f + 8); fp8x4_to_f32(q.w, f + 12);
        #pragma unroll
        for (int k = 0; k < 16; k++) acc[k] = fmaf(p, f[k], acc[k]);
    }

    float inv = 1.f / (den + 1e-16f);
    u16 ov[16];
    #pragma unroll
    for (int k = 0; k < 16; k++) {
        float a = acc[k] * inv + bias1[c0 + k];
        a = a > 0.f ? a : expm1f(a);   // ELU
        ov[k] = f2bf(a);
    }
    *(uint4*)(x2 + (size_t)dst * D1 + c0) = *(const uint4*)ov;
    *(uint4*)(x2 + (size_t)dst * D1 + c0 + 8) = *(const uint4*)(ov + 8);
}

// ---------- layer-2 per-edge weights (padded slots, fully parallel) ----------
__global__ __launch_bounds__(256) void edgew2_kernel(const int* __restrict__ csr,
                                                     const int* __restrict__ cnt,
                                                     const float* __restrict__ as2,
                                                     const float* __restrict__ ad2,
                                                     float* __restrict__ pw2) {
    int i = blockIdx.x * 256 + threadIdx.x;
    if (i >= NN * CAP) return;
    int d = i / CAP, pos = i % CAP;
    if (pos < min(cnt[d], CAP)) {
        float e = as2[csr[i]] + ad2[d];
        e = e > 0.f ? e : 0.2f * e;
        pw2[i] = __expf(e);
    }
}

// ---------- layer-2 softmax-aggregate + log_softmax ----------
// ONE WAVE per dst; idx+weight broadcast via shfl; 4B bf16 gather per edge.
__global__ __launch_bounds__(256) void agg2_kernel(const u16* __restrict__ h2,
                                                   const float* __restrict__ pw2,
                                                   const int* __restrict__ cnt,
                                                   const int* __restrict__ csr,
                                                   const float* __restrict__ bias2,
                                                   float* __restrict__ out) {
    const int tid = threadIdx.x;
    const int dst = (blockIdx.x << 2) + (tid >> 6);
    const int lane = tid & 63;
    if (dst >= NN) return;
    const int base = dst * CAP;
    const int deg = max(1, min(cnt[dst], CAP));

    float a0 = 0.f, a1 = 0.f, den = 0.f;
    int lidx = base + min(lane, deg - 1);
    int idx = csr[lidx];          // coalesced
    float pl = pw2[lidx];         // coalesced
    int j = 0;
    for (; j + 4 <= deg; j += 4) {
        int s0 = __shfl(idx, j, 64),     s1 = __shfl(idx, j + 1, 64);
        int s2 = __shfl(idx, j + 2, 64), s3 = __shfl(idx, j + 3, 64);
        float p0 = __shfl(pl, j, 64),     p1 = __shfl(pl, j + 1, 64);
        float p2 = __shfl(pl, j + 2, 64), p3 = __shfl(pl, j + 3, 64);
        unsigned int v0 = *(const unsigned int*)(h2 + (size_t)s0 * C2 + lane * 2);
        unsigned int v1 = *(const unsigned int*)(h2 + (size_t)s1 * C2 + lane * 2);
        unsigned int v2 = *(const unsigned int*)(h2 + (size_t)s2 * C2 + lane * 2);
        unsigned int v3 = *(const unsigned int*)(h2 + (size_t)s3 * C2 + lane * 2);
        den += (p0 + p1) + (p2 + p3);
        a0 = fmaf(p0, bf2f((u16)(v0 & 0xFFFF)), a0);
        a1 = fmaf(p0, bf2f((u16)(v0 >> 16)), a1);
        a0 = fmaf(p1, bf2f((u16)(v1 & 0xFFFF)), a0);
        a1 = fmaf(p1, bf2f((u16)(v1 >> 16)), a1);
        a0 = fmaf(p2, bf2f((u16)(v2 & 0xFFFF)), a0);
        a1 = fmaf(p2, bf2f((u16)(v2 >> 16)), a1);
        a0 = fmaf(p3, bf2f((u16)(v3 & 0xFFFF)), a0);
        a1 = fmaf(p3, bf2f((u16)(v3 >> 16)), a1);
    }
    for (; j < deg; j++) {
        int s = __shfl(idx, j, 64);
        float p = __shfl(pl, j, 64);
        unsigned int v = *(const unsigned int*)(h2 + (size_t)s * C2 + lane * 2);
        den += p;
        a0 = fmaf(p, bf2f((u16)(v & 0xFFFF)), a0);
        a1 = fmaf(p, bf2f((u16)(v >> 16)), a1);
    }
    float inv = 1.f / (den + 1e-16f);
    float l0 = a0 * inv + bias2[lane * 2];
    float l1 = a1 * inv + bias2[lane * 2 + 1];
    // log_softmax over the wave's 128 channels
    float m = bred_max(fmaxf(l0, l1));
    float ex = bred_sum(expf(l0 - m) + expf(l1 - m));
    float lse = m + logf(ex);
    float2 ov = {l0 - lse, l1 - lse};
    *(float2*)(out + (size_t)dst * C2 + lane * 2) = ov;
}

extern "C" void kernel_launch(void* const* d_in, const int* in_sizes, int n_in,
                              void* d_out, int out_size, void* d_ws, size_t ws_size,
                              hipStream_t stream) {
    const float* x        = (const float*)d_in[0];
    const int*   ei       = (const int*)d_in[1];
    const float* W1       = (const float*)d_in[2];
    const float* att_src1 = (const float*)d_in[3];
    const float* att_dst1 = (const float*)d_in[4];
    const float* bias1    = (const float*)d_in[5];
    const float* W2       = (const float*)d_in[6];
    const float* att_src2 = (const float*)d_in[7];
    const float* att_dst2 = (const float*)d_in[8];
    const float* bias2    = (const float*)d_in[9];
    float* out = (float*)d_out;
    const int E = in_sizes[1] / 2;
    const int NB = (NN + 255) / 256;

    char* ws = (char*)d_ws;
    size_t off = 0;
    auto alloc = [&](size_t b) {
        void* p = ws + off;
        off += (b + 255) & ~(size_t)255;
        return p;
    };
    u8*  h1q  = (u8*)alloc((size_t)NN * D1);
    u16* x2   = (u16*)alloc((size_t)NN * D1 * 2);
    u16* h2   = (u16*)alloc((size_t)NN * C2 * 2);
    u16* xb   = (u16*)alloc((size_t)NN * FIN * 2);
    u16* w1t  = (u16*)alloc((size_t)D1 * FIN * 2);
    u16* w2t  = (u16*)alloc((size_t)C2 * D1 * 2);
    float* as1 = (float*)alloc((size_t)NN * NH * 4);
    float* ad1 = (float*)alloc((size_t)NN * NH * 4);
    float* as2 = (float*)alloc((size_t)NN * 4);
    float* ad2 = (float*)alloc((size_t)NN * 4);
    int* cnt  = (int*)alloc((size_t)NN * 4);
    int* csr  = (int*)alloc((size_t)NN * CAP * 4);
    float* pw1 = (float*)alloc((size_t)NN * CAP * 8 * 4);
    float* pw2 = (float*)alloc((size_t)NN * CAP * 4);

    cast_bf16_kernel<<<(NN * FIN / 4 + 255) / 256, 256, 0, stream>>>(x, xb, NN * FIN);
    transpose_cast_kernel<<<dim3(D1 / 32, FIN / 32), 256, 0, stream>>>(W1, w1t, FIN, D1);
    transpose_cast_kernel<<<dim3(C2 / 32, D1 / 32), 256, 0, stream>>>(W2, w2t, D1, C2);
    init_cnt_kernel<<<NB, 256, 0, stream>>>(cnt, NN);

    // layer 1 GEMM: h1q fp8 + fused per-head as1/ad1
    gemm_mfma<128, 2><<<dim3((NN + 127) / 128, D1 / 128), 256, 0, stream>>>(
        xb, w1t, h1q, att_src1, att_dst1, as1, ad1, NH, NN, D1, FIN);
    fill_kernel<<<(E + NN + 255) / 256, 256, 0, stream>>>(ei, E, NN, cnt, csr,
                                                          as1, ad1, pw1);
    // 1 wave per dst: 20000 waves = 5000 blocks
    agg1_kernel<<<(NN + 3) / 4, 256, 0, stream>>>(h1q, pw1, cnt, csr, bias1, x2);
    // layer 2 GEMM: h2 bf16 + fused as2/ad2
    gemm_mfma<64, 1><<<dim3((NN + 63) / 64, C2 / 128), 256, 0, stream>>>(
        x2, w2t, h2, att_src2, att_dst2, as2, ad2, 1, NN, C2, D1);
    edgew2_kernel<<<(NN * CAP + 255) / 256, 256, 0, stream>>>(csr, cnt, as2, ad2, pw2);
    agg2_kernel<<<(NN + 3) / 4, 256, 0, stream>>>(h2, pw2, cnt, csr, bias2, out);
}

// Round 14
// 268.761 us; speedup vs baseline: 1.0504x; 1.0233x over previous
//
#include <hip/hip_runtime.h>

#define NN 20000      // nodes
#define FIN 256
#define D1 1024       // H1*C1 = 8*128
#define NH 8
#define C2 128
#define CAP 64        // padded CSR bucket capacity (max degree ~35 incl. self-loop)

typedef unsigned short u16;
typedef unsigned char u8;
typedef __attribute__((ext_vector_type(8))) short bf16x8;
typedef __attribute__((ext_vector_type(4))) float f32x4;
typedef __attribute__((ext_vector_type(2))) float f32x2;

// ---------- bf16 helpers ----------
__device__ __forceinline__ float bf2f(u16 u) {
    return __uint_as_float(((unsigned int)u) << 16);
}
__device__ __forceinline__ u16 f2bf(float f) {
    unsigned int u = __float_as_uint(f);
    u += 0x7FFFu + ((u >> 16) & 1u);   // round-to-nearest-even
    return (u16)(u >> 16);
}
// ---------- fp8 e4m3 (OCP) helpers via HW converts ----------
__device__ __forceinline__ u8 f2fp8(float v) {
    int q = __builtin_amdgcn_cvt_pk_fp8_f32(v, v, 0, false);
    return (u8)(q & 0xFF);
}
__device__ __forceinline__ void fp8x4_to_f32(unsigned int w, float* o) {
    f32x2 lo = __builtin_amdgcn_cvt_pk_f32_fp8(w, false);
    f32x2 hi = __builtin_amdgcn_cvt_pk_f32_fp8(w, true);
    o[0] = lo[0]; o[1] = lo[1]; o[2] = hi[0]; o[3] = hi[1];
}

// butterfly reductions: every lane ends with the result
__device__ __forceinline__ float bred_max(float v) {
    #pragma unroll
    for (int o = 32; o > 0; o >>= 1) v = fmaxf(v, __shfl_xor(v, o, 64));
    return v;
}
__device__ __forceinline__ float bred_sum(float v) {
    #pragma unroll
    for (int o = 32; o > 0; o >>= 1) v += __shfl_xor(v, o, 64);
    return v;
}

// async global->LDS, 16B per lane (global_load_lds_dwordx4)
typedef const __attribute__((address_space(1))) unsigned int* as1_u32p;
typedef __attribute__((address_space(3))) unsigned int* as3_u32p;
__device__ __forceinline__ void gload_lds16(const void* g, void* l) {
    __builtin_amdgcn_global_load_lds((as1_u32p)g, (as3_u32p)l, 16, 0, 0);
}

// ---------- fused prep: cast x->bf16 | transpose-cast W1 | W2 | init cnt ----------
// Block ranges: [0,5000) cast, [5000,5256) W1t, [5256,5384) W2t, [5384,...) cnt.
__global__ __launch_bounds__(256) void prep_kernel(const float* __restrict__ x,
                                                   u16* __restrict__ xb,
                                                   const float* __restrict__ W1,
                                                   u16* __restrict__ w1t,
                                                   const float* __restrict__ W2,
                                                   u16* __restrict__ w2t,
                                                   int* __restrict__ cnt) {
    __shared__ float tile[32][33];
    const int b = blockIdx.x, tid = threadIdx.x;
    if (b < 5000) {
        int i = (b * 256 + tid) * 4;
        if (i < NN * FIN) {
            float4 v = *(const float4*)(x + i);
            ushort4 o;
            o.x = f2bf(v.x); o.y = f2bf(v.y); o.z = f2bf(v.z); o.w = f2bf(v.w);
            *(ushort4*)(xb + i) = o;
        }
        return;
    }
    if (b < 5384) {
        const float* in; u16* out; int R, C, bx, by;
        if (b < 5256) {
            int q = b - 5000;                 // W1: [FIN x D1] -> [D1 x FIN]
            in = W1; out = w1t; R = FIN; C = D1;
            bx = (q & 31) * 32; by = (q >> 5) * 32;
        } else {
            int q = b - 5256;                 // W2: [D1 x C2] -> [C2 x D1]
            in = W2; out = w2t; R = D1; C = C2;
            bx = (q & 3) * 32; by = (q >> 2) * 32;
        }
        int tx = tid & 31, ty = tid >> 5;     // 32x8
        #pragma unroll
        for (int i = 0; i < 32; i += 8)
            tile[ty + i][tx] = in[(size_t)(by + ty + i) * C + bx + tx];
        __syncthreads();
        #pragma unroll
        for (int i = 0; i < 32; i += 8)
            out[(size_t)(bx + ty + i) * R + by + tx] = f2bf(tile[tx][ty + i]);
        return;
    }
    int i = (b - 5384) * 256 + tid;
    if (i < NN) cnt[i] = 0;
}

// ---------- bf16 MFMA GEMM (BK=32) with fused attention-score epilogue ----------
// C[MxN] = A[MxK] * Bt[NxK]^T.  Block col bj covers cols [bj*128,(bj+1)*128)
// = exactly one attention head, so each block computes COMPLETE per-row
// as/ad = sum_col h[row][col]*att[col] from its fp32 accumulators.
// OMODE 1: bf16 C out (layer 2; head=0, NHo=1)
// OMODE 2: fp8 e4m3 C out only (layer 1; head=blockIdx.y, NHo=8)
template <int BM, int OMODE>
__global__ __launch_bounds__(256) void gemm_mfma(const u16* __restrict__ A,
                                                 const u16* __restrict__ Bt,
                                                 void* __restrict__ C,
                                                 const float* __restrict__ attS,
                                                 const float* __restrict__ attD,
                                                 float* __restrict__ as_out,
                                                 float* __restrict__ ad_out,
                                                 int NHo,
                                                 int M, int N, int K) {
    constexpr int TM = BM / 32;            // 16-tiles per wave along m
    __shared__ u16 ldsA[BM * 32];
    __shared__ u16 ldsB[128 * 32];
    __shared__ float asb[BM], adb[BM];
    const int tid = threadIdx.x;
    const int lane = tid & 63, w = tid >> 6;
    const int wr = w >> 1, wc = w & 1;
    const int row0 = blockIdx.x * BM, col0 = blockIdx.y * 128;
    const int head = blockIdx.y;
    const int l15 = lane & 15, quad = lane >> 4;

    for (int t = tid; t < BM; t += 256) { asb[t] = 0.f; adb[t] = 0.f; }

    f32x4 acc[TM][4];
    #pragma unroll
    for (int i = 0; i < TM; i++)
        #pragma unroll
        for (int j = 0; j < 4; j++)
            acc[i][j] = (f32x4){0.f, 0.f, 0.f, 0.f};

    for (int k0 = 0; k0 < K; k0 += 32) {
        #pragma unroll
        for (int i = 0; i < BM / 64; i++) {
            int c = tid + i * 256;
            int r = c >> 2, ko = (c & 3) * 8;
            int gr = row0 + r; if (gr >= M) gr = M - 1;  // clamp: rows >=M never stored
            gload_lds16(A + (size_t)gr * K + k0 + ko, ldsA + c * 8);
        }
        #pragma unroll
        for (int i = 0; i < 2; i++) {
            int c = tid + i * 256;
            int n = c >> 2, ko = (c & 3) * 8;
            gload_lds16(Bt + (size_t)(col0 + n) * K + k0 + ko, ldsB + c * 8);
        }
        __syncthreads();
        bf16x8 af[TM], bfr[4];
        #pragma unroll
        for (int i = 0; i < TM; i++) {
            int m = wr * (BM / 2) + i * 16 + l15;
            af[i] = *(const bf16x8*)(ldsA + m * 32 + quad * 8);
        }
        #pragma unroll
        for (int j = 0; j < 4; j++) {
            int n = wc * 64 + j * 16 + l15;
            bfr[j] = *(const bf16x8*)(ldsB + n * 32 + quad * 8);
        }
        #pragma unroll
        for (int i = 0; i < TM; i++)
            #pragma unroll
            for (int j = 0; j < 4; j++)
                acc[i][j] = __builtin_amdgcn_mfma_f32_16x16x32_bf16(af[i], bfr[j], acc[i][j], 0, 0, 0);
        __syncthreads();
    }
    // ---- C write (fp8 for layer1, bf16 for layer2) ----
    #pragma unroll
    for (int i = 0; i < TM; i++) {
        #pragma unroll
        for (int j = 0; j < 4; j++) {
            #pragma unroll
            for (int r = 0; r < 4; r++) {
                int row = row0 + wr * (BM / 2) + i * 16 + quad * 4 + r;
                int col = col0 + wc * 64 + j * 16 + l15;
                if (row < M) {
                    float v = acc[i][j][r];
                    if (OMODE == 1)
                        ((u16*)C)[(size_t)row * N + col] = f2bf(v);
                    else
                        ((u8*)C)[(size_t)row * N + col] = f2fp8(v);
                }
            }
        }
    }
    // ---- fused per-row attention dots for this head ----
    float attS_r[4], attD_r[4];
    #pragma unroll
    for (int j = 0; j < 4; j++) {
        int col = wc * 64 + j * 16 + l15;
        attS_r[j] = attS[head * 128 + col];
        attD_r[j] = attD[head * 128 + col];
    }
    #pragma unroll
    for (int i = 0; i < TM; i++) {
        #pragma unroll
        for (int r = 0; r < 4; r++) {
            float ps = 0.f, pd = 0.f;
            #pragma unroll
            for (int j = 0; j < 4; j++) {
                float v = acc[i][j][r];
                ps = fmaf(v, attS_r[j], ps);
                pd = fmaf(v, attD_r[j], pd);
            }
            #pragma unroll
            for (int o = 1; o < 16; o <<= 1) {
                ps += __shfl_xor(ps, o, 64);
                pd += __shfl_xor(pd, o, 64);
            }
            if (l15 == 0) {
                int row = wr * (BM / 2) + i * 16 + quad * 4 + r;
                atomicAdd(&asb[row], ps);
                atomicAdd(&adb[row], pd);
            }
        }
    }
    __syncthreads();
    for (int t = tid; t < BM; t += 256) {
        int row = row0 + t;
        if (row < M) {
            as_out[(size_t)row * NHo + head] = asb[t];
            ad_out[(size_t)row * NHo + head] = adb[t];
        }
    }
}

// ---------- padded-bucket CSR fill + layer-1 edge weights (8 heads) ----------
__global__ void fill_kernel(const int* __restrict__ ei, int E, int N,
                            int* __restrict__ cnt,
                            int* __restrict__ csr,
                            const float* __restrict__ as1,
                            const float* __restrict__ ad1,
                            float* __restrict__ pw1) {
    int j = blockIdx.x * 256 + threadIdx.x;
    if (j >= E + N) return;
    int s, d;
    if (j < E) { s = ei[j]; d = ei[E + j]; }
    else { s = j - E; d = j - E; }
    int pos = atomicAdd(&cnt[d], 1);
    if (pos >= CAP) return;   // safety net (never expected)
    int slot = d * CAP + pos;
    csr[slot] = s;
    float4 s0 = *(const float4*)(as1 + s * NH);
    float4 s1 = *(const float4*)(as1 + s * NH + 4);
    float4 d0 = *(const float4*)(ad1 + d * NH);
    float4 d1 = *(const float4*)(ad1 + d * NH + 4);
    float e[8] = {s0.x + d0.x, s0.y + d0.y, s0.z + d0.z, s0.w + d0.w,
                  s1.x + d1.x, s1.y + d1.y, s1.z + d1.z, s1.w + d1.w};
    float p[8];
    #pragma unroll
    for (int h = 0; h < 8; h++) {
        float v = e[h] > 0.f ? e[h] : 0.2f * e[h];
        p[h] = __expf(v);
    }
    *(float4*)(pw1 + (size_t)slot * 8) = *(const float4*)p;
    *(float4*)(pw1 + (size_t)slot * 8 + 4) = *(const float4*)(p + 4);
}

// ---------- layer-1 softmax-aggregate + ELU ----------
// ONE WAVE per dst, padded bucket. Coalesced csr load, idx broadcast via
// shfl; pre-computed weights (sequential read); x4 unroll -> 4 independent
// 16B fp8 gathers in flight. No LDS/barriers/atomics.
__global__ __launch_bounds__(256) void agg1_kernel(const u8* __restrict__ h1q,
                                                   const float* __restrict__ pw1,
                                                   const int* __restrict__ cnt,
                                                   const int* __restrict__ csr,
                                                   const float* __restrict__ bias1,
                                                   u16* __restrict__ x2) {
    const int tid = threadIdx.x;
    const int dst = (blockIdx.x << 2) + (tid >> 6);
    const int lane = tid & 63;
    if (dst >= NN) return;
    const int c0 = lane * 16;               // 16 channels per lane
    const int h = lane >> 3;                // head
    const int base = dst * CAP;
    const int deg = max(1, min(cnt[dst], CAP));

    float acc[16];
    #pragma unroll
    for (int k = 0; k < 16; k++) acc[k] = 0.f;
    float den = 0.f;

    int idx = csr[base + min(lane, deg - 1)];       // coalesced
    const float* pwc = pw1 + (size_t)base * 8 + h;  // sequential (stride 32B)
    int j = 0;
    for (; j + 4 <= deg; j += 4) {
        int s0 = __shfl(idx, j, 64),     s1 = __shfl(idx, j + 1, 64);
        int s2 = __shfl(idx, j + 2, 64), s3 = __shfl(idx, j + 3, 64);
        uint4 q0 = *(const uint4*)(h1q + (size_t)s0 * D1 + c0);
        uint4 q1 = *(const uint4*)(h1q + (size_t)s1 * D1 + c0);
        uint4 q2 = *(const uint4*)(h1q + (size_t)s2 * D1 + c0);
        uint4 q3 = *(const uint4*)(h1q + (size_t)s3 * D1 + c0);
        float p0 = pwc[(j + 0) * 8], p1 = pwc[(j + 1) * 8];
        float p2 = pwc[(j + 2) * 8], p3 = pwc[(j + 3) * 8];
        den += (p0 + p1) + (p2 + p3);
        float f[16];
        fp8x4_to_f32(q0.x, f + 0); fp8x4_to_f32(q0.y, f + 4);
        fp8x4_to_f32(q0.z, f + 8); fp8x4_to_f32(q0.w, f + 12);
        #pragma unroll
        for (int k = 0; k < 16; k++) acc[k] = fmaf(p0, f[k], acc[k]);
        fp8x4_to_f32(q1.x, f + 0); fp8x4_to_f32(q1.y, f + 4);
        fp8x4_to_f32(q1.z, f + 8); fp8x4_to_f32(q1.w, f + 12);
        #pragma unroll
        for (int k = 0; k < 16; k++) acc[k] = fmaf(p1, f[k], acc[k]);
        fp8x4_to_f32(q2.x, f + 0); fp8x4_to_f32(q2.y, f + 4);
        fp8x4_to_f32(q2.z, f + 8); fp8x4_to_f32(q2.w, f + 12);
        #pragma unroll
        for (int k = 0; k < 16; k++) acc[k] = fmaf(p2, f[k], acc[k]);
        fp8x4_to_f32(q3.x, f + 0); fp8x4_to_f32(q3.y, f + 4);
        fp8x4_to_f32(q3.z, f + 8); fp8x4_to_f32(q3.w, f + 12);
        #pragma unroll
        for (int k = 0; k < 16; k++) acc[k] = fmaf(p3, f[k], acc[k]);
    }
    for (; j < deg; j++) {
        int s = __shfl(idx, j, 64);
        float p = pwc[j * 8];
        uint4 q = *(const uint4*)(h1q + (size_t)s * D1 + c0);
        den += p;
        float f[16];
        fp8x4_to_f32(q.x, f + 0); fp8x4_to_f32(q.y, f + 4);
        fp8x4_to_f32(q.z, f + 8); fp8x4_to_f32(q.w, f + 12);
        #pragma unroll
        for (int k = 0; k < 16; k++) acc[k] = fmaf(p, f[k], acc[k]);
    }

    float inv = 1.f / (den + 1e-16f);
    u16 ov[16];
    #pragma unroll
    for (int k = 0; k < 16; k++) {
        float a = acc[k] * inv + bias1[c0 + k];
        a = a > 0.f ? a : expm1f(a);   // ELU
        ov[k] = f2bf(a);
    }
    *(uint4*)(x2 + (size_t)dst * D1 + c0) = *(const uint4*)ov;
    *(uint4*)(x2 + (size_t)dst * D1 + c0 + 8) = *(const uint4*)(ov + 8);
}

// ---------- layer-2 softmax-aggregate + log_softmax (inline edge weights) ----------
// ONE WAVE per dst. Lane l computes p for edge l inline (as2 is an 80 KB
// L2-resident table); idx+weight broadcast via shfl; 4B bf16 gather per edge.
__global__ __launch_bounds__(256) void agg2_kernel(const u16* __restrict__ h2,
                                                   const float* __restrict__ as2,
                                                   const float* __restrict__ ad2,
                                                   const int* __restrict__ cnt,
                                                   const int* __restrict__ csr,
                                                   const float* __restrict__ bias2,
                                                   float* __restrict__ out) {
    const int tid = threadIdx.x;
    const int dst = (blockIdx.x << 2) + (tid >> 6);
    const int lane = tid & 63;
    if (dst >= NN) return;
    const int base = dst * CAP;
    const int deg = max(1, min(cnt[dst], CAP));
    const float adv = ad2[dst];

    int idx = csr[base + min(lane, deg - 1)];   // coalesced
    float e = as2[idx] + adv;                   // random 4B within 80 KB (L2-hit)
    e = e > 0.f ? e : 0.2f * e;
    float pl = __expf(e);

    float a0 = 0.f, a1 = 0.f, den = 0.f;
    int j = 0;
    for (; j + 4 <= deg; j += 4) {
        int s0 = __shfl(idx, j, 64),     s1 = __shfl(idx, j + 1, 64);
        int s2 = __shfl(idx, j + 2, 64), s3 = __shfl(idx, j + 3, 64);
        float p0 = __shfl(pl, j, 64),     p1 = __shfl(pl, j + 1, 64);
        float p2 = __shfl(pl, j + 2, 64), p3 = __shfl(pl, j + 3, 64);
        unsigned int v0 = *(const unsigned int*)(h2 + (size_t)s0 * C2 + lane * 2);
        unsigned int v1 = *(const unsigned int*)(h2 + (size_t)s1 * C2 + lane * 2);
        unsigned int v2 = *(const unsigned int*)(h2 + (size_t)s2 * C2 + lane * 2);
        unsigned int v3 = *(const unsigned int*)(h2 + (size_t)s3 * C2 + lane * 2);
        den += (p0 + p1) + (p2 + p3);
        a0 = fmaf(p0, bf2f((u16)(v0 & 0xFFFF)), a0);
        a1 = fmaf(p0, bf2f((u16)(v0 >> 16)), a1);
        a0 = fmaf(p1, bf2f((u16)(v1 & 0xFFFF)), a0);
        a1 = fmaf(p1, bf2f((u16)(v1 >> 16)), a1);
        a0 = fmaf(p2, bf2f((u16)(v2 & 0xFFFF)), a0);
        a1 = fmaf(p2, bf2f((u16)(v2 >> 16)), a1);
        a0 = fmaf(p3, bf2f((u16)(v3 & 0xFFFF)), a0);
        a1 = fmaf(p3, bf2f((u16)(v3 >> 16)), a1);
    }
    for (; j < deg; j++) {
        int s = __shfl(idx, j, 64);
        float p = __shfl(pl, j, 64);
        unsigned int v = *(const unsigned int*)(h2 + (size_t)s * C2 + lane * 2);
        den += p;
        a0 = fmaf(p, bf2f((u16)(v & 0xFFFF)), a0);
        a1 = fmaf(p, bf2f((u16)(v >> 16)), a1);
    }
    float inv = 1.f / (den + 1e-16f);
    float l0 = a0 * inv + bias2[lane * 2];
    float l1 = a1 * inv + bias2[lane * 2 + 1];
    // log_softmax over the wave's 128 channels
    float m = bred_max(fmaxf(l0, l1));
    float ex = bred_sum(expf(l0 - m) + expf(l1 - m));
    float lse = m + logf(ex);
    float2 ov = {l0 - lse, l1 - lse};
    *(float2*)(out + (size_t)dst * C2 + lane * 2) = ov;
}

extern "C" void kernel_launch(void* const* d_in, const int* in_sizes, int n_in,
                              void* d_out, int out_size, void* d_ws, size_t ws_size,
                              hipStream_t stream) {
    const float* x        = (const float*)d_in[0];
    const int*   ei       = (const int*)d_in[1];
    const float* W1       = (const float*)d_in[2];
    const float* att_src1 = (const float*)d_in[3];
    const float* att_dst1 = (const float*)d_in[4];
    const float* bias1    = (const float*)d_in[5];
    const float* W2       = (const float*)d_in[6];
    const float* att_src2 = (const float*)d_in[7];
    const float* att_dst2 = (const float*)d_in[8];
    const float* bias2    = (const float*)d_in[9];
    float* out = (float*)d_out;
    const int E = in_sizes[1] / 2;

    char* ws = (char*)d_ws;
    size_t off = 0;
    auto alloc = [&](size_t b) {
        void* p = ws + off;
        off += (b + 255) & ~(size_t)255;
        return p;
    };
    u8*  h1q  = (u8*)alloc((size_t)NN * D1);
    u16* x2   = (u16*)alloc((size_t)NN * D1 * 2);
    u16* h2   = (u16*)alloc((size_t)NN * C2 * 2);
    u16* xb   = (u16*)alloc((size_t)NN * FIN * 2);
    u16* w1t  = (u16*)alloc((size_t)D1 * FIN * 2);
    u16* w2t  = (u16*)alloc((size_t)C2 * D1 * 2);
    float* as1 = (float*)alloc((size_t)NN * NH * 4);
    float* ad1 = (float*)alloc((size_t)NN * NH * 4);
    float* as2 = (float*)alloc((size_t)NN * 4);
    float* ad2 = (float*)alloc((size_t)NN * 4);
    int* cnt  = (int*)alloc((size_t)NN * 4);
    int* csr  = (int*)alloc((size_t)NN * CAP * 4);
    float* pw1 = (float*)alloc((size_t)NN * CAP * 8 * 4);

    // fused prep: cast x, transpose W1/W2, zero cnt
    const int PREP_BLOCKS = 5000 + 256 + 128 + (NN + 255) / 256;
    prep_kernel<<<PREP_BLOCKS, 256, 0, stream>>>(x, xb, W1, w1t, W2, w2t, cnt);

    // layer 1 GEMM: h1q fp8 + fused per-head as1/ad1
    gemm_mfma<128, 2><<<dim3((NN + 127) / 128, D1 / 128), 256, 0, stream>>>(
        xb, w1t, h1q, att_src1, att_dst1, as1, ad1, NH, NN, D1, FIN);
    fill_kernel<<<(E + NN + 255) / 256, 256, 0, stream>>>(ei, E, NN, cnt, csr,
                                                          as1, ad1, pw1);
    // 1 wave per dst: 20000 waves = 5000 blocks
    agg1_kernel<<<(NN + 3) / 4, 256, 0, stream>>>(h1q, pw1, cnt, csr, bias1, x2);
    // layer 2 GEMM: h2 bf16 + fused as2/ad2
    gemm_mfma<64, 1><<<dim3((NN + 63) / 64, C2 / 128), 256, 0, stream>>>(
        x2, w2t, h2, att_src2, att_dst2, as2, ad2, 1, NN, C2, D1);
    agg2_kernel<<<(NN + 3) / 4, 256, 0, stream>>>(h2, as2, ad2, cnt, csr, bias2, out);
}